// Round 1
// baseline (2447.776 us; speedup 1.0000x reference)
//
#include <hip/hip_runtime.h>
#include <hip/hip_bf16.h>
#include <math.h>

#define T_SEQ 1024
#define BSZ   8
#define EMB   1280
#define NH    20
#define HD    64
#define MROWS (T_SEQ * BSZ)   // 8192

// ---------------------------------------------------------------------------
// RoPE cos/sin table: [T_SEQ][32]  (ESM: inv_freq over even dims, emb=concat)
// ---------------------------------------------------------------------------
__global__ void rope_table_kernel(float* __restrict__ cost, float* __restrict__ sint) {
    int idx = blockIdx.x * blockDim.x + threadIdx.x;   // t*32 + i
    if (idx >= T_SEQ * 32) return;
    int i = idx & 31;
    int t = idx >> 5;
    double inv = pow(10000.0, -(double)i / 32.0);
    float f = (float)((double)t * inv);          // fp32 freqs like the reference
    cost[idx] = (float)cos((double)f);
    sint[idx] = (float)sin((double)f);
}

// ---------------------------------------------------------------------------
// QKV projection: out[r,o] = sum_e X[r,e]*W[o,e] + b[o]  (NT GEMM),
// written directly in [B,H,T,D] layout.  64x64 tile, BK=16, 4x4 per thread.
// ---------------------------------------------------------------------------
__global__ __launch_bounds__(256) void qkv_gemm_kernel(
    const float* __restrict__ X,
    const float* __restrict__ Wq, const float* __restrict__ Wk, const float* __restrict__ Wv,
    const float* __restrict__ Bq, const float* __restrict__ Bk, const float* __restrict__ Bv,
    float* __restrict__ Oq, float* __restrict__ Ok, float* __restrict__ Ov)
{
    const int which = blockIdx.z;
    const float* __restrict__ W  = (which == 0) ? Wq : (which == 1) ? Wk : Wv;
    const float* __restrict__ Bb = (which == 0) ? Bq : (which == 1) ? Bk : Bv;
    float* __restrict__ O        = (which == 0) ? Oq : (which == 1) ? Ok : Ov;

    __shared__ float As[16][68];   // [k][row], pad 68 -> 2-way max on all patterns
    __shared__ float Bs[16][68];

    const int tid = threadIdx.x;
    const int tx = tid & 15;
    const int ty = tid >> 4;
    const int m0 = blockIdx.x * 64;
    const int n0 = blockIdx.y * 64;
    const int lr = tid >> 2;          // 0..63 tile row
    const int lk = (tid & 3) << 2;    // 0,4,8,12 k offset

    const float* aptr = X + (size_t)(m0 + lr) * EMB + lk;
    const float* bptr = W + (size_t)(n0 + lr) * EMB + lk;

    float acc[4][4] = {};

    for (int k0 = 0; k0 < EMB; k0 += 16) {
        float4 a = *(const float4*)(aptr + k0);
        float4 b = *(const float4*)(bptr + k0);
        __syncthreads();
        As[lk + 0][lr] = a.x; As[lk + 1][lr] = a.y; As[lk + 2][lr] = a.z; As[lk + 3][lr] = a.w;
        Bs[lk + 0][lr] = b.x; Bs[lk + 1][lr] = b.y; Bs[lk + 2][lr] = b.z; Bs[lk + 3][lr] = b.w;
        __syncthreads();
        #pragma unroll
        for (int kk = 0; kk < 16; ++kk) {
            float4 a4 = *(const float4*)&As[kk][ty << 2];
            float4 b4 = *(const float4*)&Bs[kk][tx << 2];
            float aa[4] = {a4.x, a4.y, a4.z, a4.w};
            float bb[4] = {b4.x, b4.y, b4.z, b4.w};
            #pragma unroll
            for (int i = 0; i < 4; ++i)
                #pragma unroll
                for (int j = 0; j < 4; ++j)
                    acc[i][j] += aa[i] * bb[j];
        }
    }

    // epilogue: bias + scatter to [B,H,T,D]; 64-wide tile == one head
    const float4 bias4 = *(const float4*)&Bb[n0 + (tx << 2)];
    const int h = blockIdx.y;
    #pragma unroll
    for (int i = 0; i < 4; ++i) {
        int r = m0 + (ty << 2) + i;
        int t  = r >> 3;
        int b_ = r & 7;
        float4 o;
        o.x = acc[i][0] + bias4.x;
        o.y = acc[i][1] + bias4.y;
        o.z = acc[i][2] + bias4.z;
        o.w = acc[i][3] + bias4.w;
        *(float4*)&O[(((size_t)b_ * NH + h) * T_SEQ + t) * HD + (tx << 2)] = o;
    }
}

// ---------------------------------------------------------------------------
// Output projection: same GEMM, row-major [T,B,E] output (direct to d_out)
// ---------------------------------------------------------------------------
__global__ __launch_bounds__(256) void out_gemm_kernel(
    const float* __restrict__ X, const float* __restrict__ W,
    const float* __restrict__ Bb, float* __restrict__ O)
{
    __shared__ float As[16][68];
    __shared__ float Bs[16][68];

    const int tid = threadIdx.x;
    const int tx = tid & 15;
    const int ty = tid >> 4;
    const int m0 = blockIdx.x * 64;
    const int n0 = blockIdx.y * 64;
    const int lr = tid >> 2;
    const int lk = (tid & 3) << 2;

    const float* aptr = X + (size_t)(m0 + lr) * EMB + lk;
    const float* bptr = W + (size_t)(n0 + lr) * EMB + lk;

    float acc[4][4] = {};

    for (int k0 = 0; k0 < EMB; k0 += 16) {
        float4 a = *(const float4*)(aptr + k0);
        float4 b = *(const float4*)(bptr + k0);
        __syncthreads();
        As[lk + 0][lr] = a.x; As[lk + 1][lr] = a.y; As[lk + 2][lr] = a.z; As[lk + 3][lr] = a.w;
        Bs[lk + 0][lr] = b.x; Bs[lk + 1][lr] = b.y; Bs[lk + 2][lr] = b.z; Bs[lk + 3][lr] = b.w;
        __syncthreads();
        #pragma unroll
        for (int kk = 0; kk < 16; ++kk) {
            float4 a4 = *(const float4*)&As[kk][ty << 2];
            float4 b4 = *(const float4*)&Bs[kk][tx << 2];
            float aa[4] = {a4.x, a4.y, a4.z, a4.w};
            float bb[4] = {b4.x, b4.y, b4.z, b4.w};
            #pragma unroll
            for (int i = 0; i < 4; ++i)
                #pragma unroll
                for (int j = 0; j < 4; ++j)
                    acc[i][j] += aa[i] * bb[j];
        }
    }

    const float4 bias4 = *(const float4*)&Bb[n0 + (tx << 2)];
    #pragma unroll
    for (int i = 0; i < 4; ++i) {
        int r = m0 + (ty << 2) + i;
        float4 o;
        o.x = acc[i][0] + bias4.x;
        o.y = acc[i][1] + bias4.y;
        o.z = acc[i][2] + bias4.z;
        o.w = acc[i][3] + bias4.w;
        *(float4*)&O[(size_t)r * EMB + n0 + (tx << 2)] = o;
    }
}

// ---------------------------------------------------------------------------
// RoPE in-place on q and k in [B,H,T,D]: one thread per (bh, t, pair i)
// ---------------------------------------------------------------------------
__global__ void rope_apply_kernel(float* __restrict__ q, float* __restrict__ k,
                                  const float* __restrict__ cost,
                                  const float* __restrict__ sint)
{
    int idx = blockIdx.x * blockDim.x + threadIdx.x;   // bh*T*32 + t*32 + i
    int i = idx & 31;
    int t = (idx >> 5) & (T_SEQ - 1);
    int bh = idx >> 15;
    size_t base = ((size_t)bh * T_SEQ + t) * HD;
    float c = cost[t * 32 + i];
    float s = sint[t * 32 + i];
    float q1 = q[base + i], q2 = q[base + 32 + i];
    q[base + i]      = q1 * c - q2 * s;
    q[base + 32 + i] = q2 * c + q1 * s;
    float k1 = k[base + i], k2 = k[base + 32 + i];
    k[base + i]      = k1 * c - k2 * s;
    k[base + 32 + i] = k2 * c + k1 * s;
}

// ---------------------------------------------------------------------------
// Flash-style attention: block = (64 q-rows, one bh). Online softmax in fp32.
// LDS: Qs,Ks,Vs,Ps 64x68 each (~70 KB -> 2 blocks/CU).
// ---------------------------------------------------------------------------
__global__ __launch_bounds__(256) void attn_kernel(
    const float* __restrict__ Q, const float* __restrict__ K,
    const float* __restrict__ V, float* __restrict__ A)
{
    __shared__ float Qs[64][68];
    __shared__ float Ks[64][68];
    __shared__ float Vs[64][68];
    __shared__ float Ps[64][68];

    const int tid = threadIdx.x;
    const int tx = tid & 15;
    const int ty = tid >> 4;
    const int bh = blockIdx.y;          // 0..159
    const int b_ = bh / NH;
    const int h  = bh % NH;
    const int q0 = blockIdx.x * 64;
    const float scaling = 0.125f;       // 64^-0.5

    const float* Qbh = Q + (size_t)bh * T_SEQ * HD;
    const float* Kbh = K + (size_t)bh * T_SEQ * HD;
    const float* Vbh = V + (size_t)bh * T_SEQ * HD;

    // stage Q tile (pre-scaled)
    {
        int row = tid >> 4;             // 0..15
        int col = (tid & 15) << 2;      // 0..60
        #pragma unroll
        for (int rr = 0; rr < 4; ++rr) {
            float4 v = *(const float4*)&Qbh[(size_t)(q0 + rr * 16 + row) * HD + col];
            v.x *= scaling; v.y *= scaling; v.z *= scaling; v.w *= scaling;
            *(float4*)&Qs[rr * 16 + row][col] = v;
        }
    }

    float o[4][4];
    float m_i[4], l_i[4];
    #pragma unroll
    for (int i = 0; i < 4; ++i) {
        m_i[i] = -INFINITY; l_i[i] = 0.f;
        o[i][0] = o[i][1] = o[i][2] = o[i][3] = 0.f;
    }

    for (int kt = 0; kt < T_SEQ / 64; ++kt) {
        __syncthreads();  // protect Qs (iter0) / Ps,Vs (prev iter) before overwrite
        {
            int row = tid >> 4;
            int col = (tid & 15) << 2;
            #pragma unroll
            for (int rr = 0; rr < 4; ++rr) {
                *(float4*)&Ks[rr * 16 + row][col] =
                    *(const float4*)&Kbh[(size_t)(kt * 64 + rr * 16 + row) * HD + col];
                *(float4*)&Vs[rr * 16 + row][col] =
                    *(const float4*)&Vbh[(size_t)(kt * 64 + rr * 16 + row) * HD + col];
            }
        }
        __syncthreads();

        // scores: q-row = ty*4+i, k-col = tx + 16*j   (strided cols: 2-way banks max)
        float s[4][4] = {};
        #pragma unroll
        for (int kk4 = 0; kk4 < 16; ++kk4) {
            float4 q4[4], k4[4];
            #pragma unroll
            for (int i = 0; i < 4; ++i) q4[i] = *(const float4*)&Qs[(ty << 2) + i][kk4 << 2];
            #pragma unroll
            for (int j = 0; j < 4; ++j) k4[j] = *(const float4*)&Ks[tx + (j << 4)][kk4 << 2];
            #pragma unroll
            for (int i = 0; i < 4; ++i)
                #pragma unroll
                for (int j = 0; j < 4; ++j)
                    s[i][j] += q4[i].x * k4[j].x + q4[i].y * k4[j].y
                             + q4[i].z * k4[j].z + q4[i].w * k4[j].w;
        }

        // online softmax update (row groups = 16 contiguous lanes within a wave)
        #pragma unroll
        for (int i = 0; i < 4; ++i) {
            float tm = fmaxf(fmaxf(s[i][0], s[i][1]), fmaxf(s[i][2], s[i][3]));
            tm = fmaxf(tm, __shfl_xor(tm, 1));
            tm = fmaxf(tm, __shfl_xor(tm, 2));
            tm = fmaxf(tm, __shfl_xor(tm, 4));
            tm = fmaxf(tm, __shfl_xor(tm, 8));
            float mn   = fmaxf(m_i[i], tm);
            float corr = __expf(m_i[i] - mn);   // 0 on first tile
            m_i[i] = mn;
            float rs = 0.f;
            #pragma unroll
            for (int j = 0; j < 4; ++j) {
                float p = __expf(s[i][j] - mn);
                s[i][j] = p;
                rs += p;
            }
            rs += __shfl_xor(rs, 1);
            rs += __shfl_xor(rs, 2);
            rs += __shfl_xor(rs, 4);
            rs += __shfl_xor(rs, 8);
            l_i[i] = l_i[i] * corr + rs;
            o[i][0] *= corr; o[i][1] *= corr; o[i][2] *= corr; o[i][3] *= corr;
            Ps[(ty << 2) + i][tx     ] = s[i][0];
            Ps[(ty << 2) + i][tx + 16] = s[i][1];
            Ps[(ty << 2) + i][tx + 32] = s[i][2];
            Ps[(ty << 2) + i][tx + 48] = s[i][3];
        }
        __syncthreads();

        // PV: o[i][0..3] (d = tx*4..) += P[row][kk] * V[kk][d]
        #pragma unroll
        for (int kk4 = 0; kk4 < 16; ++kk4) {
            float pa[4][4];
            #pragma unroll
            for (int i = 0; i < 4; ++i) {
                float4 p4 = *(const float4*)&Ps[(ty << 2) + i][kk4 << 2];
                pa[i][0] = p4.x; pa[i][1] = p4.y; pa[i][2] = p4.z; pa[i][3] = p4.w;
            }
            #pragma unroll
            for (int kk = 0; kk < 4; ++kk) {
                float4 v4 = *(const float4*)&Vs[(kk4 << 2) + kk][tx << 2];
                #pragma unroll
                for (int i = 0; i < 4; ++i) {
                    o[i][0] += pa[i][kk] * v4.x;
                    o[i][1] += pa[i][kk] * v4.y;
                    o[i][2] += pa[i][kk] * v4.z;
                    o[i][3] += pa[i][kk] * v4.w;
                }
            }
        }
    }

    // final: normalize and scatter to [T,B,E]
    #pragma unroll
    for (int i = 0; i < 4; ++i) {
        float inv = 1.0f / l_i[i];
        int t = q0 + (ty << 2) + i;
        float4 o4;
        o4.x = o[i][0] * inv; o4.y = o[i][1] * inv;
        o4.z = o[i][2] * inv; o4.w = o[i][3] * inv;
        *(float4*)&A[((size_t)t * BSZ + b_) * EMB + h * HD + (tx << 2)] = o4;
    }
}

// ---------------------------------------------------------------------------
extern "C" void kernel_launch(void* const* d_in, const int* in_sizes, int n_in,
                              void* d_out, int out_size, void* d_ws, size_t ws_size,
                              hipStream_t stream) {
    const float* X     = (const float*)d_in[0];
    const float* q_w   = (const float*)d_in[1];
    const float* q_b   = (const float*)d_in[2];
    const float* k_w   = (const float*)d_in[3];
    const float* k_b   = (const float*)d_in[4];
    const float* v_w   = (const float*)d_in[5];
    const float* v_b   = (const float*)d_in[6];
    const float* out_w = (const float*)d_in[7];
    const float* out_b = (const float*)d_in[8];
    float* out = (float*)d_out;

    float* ws = (float*)d_ws;
    const size_t NELT = (size_t)MROWS * EMB;   // 10485760 floats
    float* q_ws = ws;
    float* k_ws = q_ws + NELT;
    float* v_ws = k_ws + NELT;
    float* a_ws = v_ws + NELT;
    float* cost = a_ws + NELT;
    float* sint = cost + T_SEQ * 32;

    rope_table_kernel<<<dim3((T_SEQ * 32 + 255) / 256), 256, 0, stream>>>(cost, sint);

    qkv_gemm_kernel<<<dim3(MROWS / 64, EMB / 64, 3), 256, 0, stream>>>(
        X, q_w, k_w, v_w, q_b, k_b, v_b, q_ws, k_ws, v_ws);

    rope_apply_kernel<<<dim3((BSZ * NH * T_SEQ * 32) / 256), 256, 0, stream>>>(
        q_ws, k_ws, cost, sint);

    attn_kernel<<<dim3(T_SEQ / 64, BSZ * NH), 256, 0, stream>>>(
        q_ws, k_ws, v_ws, a_ws);

    out_gemm_kernel<<<dim3(MROWS / 64, EMB / 64), 256, 0, stream>>>(
        a_ws, out_w, out_b, out);
}

// Round 2
// 445.290 us; speedup vs baseline: 5.4970x; 5.4970x over previous
//
#include <hip/hip_runtime.h>
#include <math.h>

#define T_SEQ 1024
#define BSZ   8
#define EMB   1280
#define NH    20
#define HD    64
#define MROWS 8192
#define KBYTES (EMB * 2)

typedef __attribute__((ext_vector_type(8))) short bf16x8;
typedef __attribute__((ext_vector_type(4))) float f32x4;

__device__ __forceinline__ short f2bf(float f) {
    unsigned u = __float_as_uint(f);
    u += 0x7fff + ((u >> 16) & 1);           // RNE
    return (short)(u >> 16);
}
__device__ __forceinline__ float bf2f(short s) {
    return __uint_as_float(((unsigned)(unsigned short)s) << 16);
}

// async global->LDS, 16B per lane; LDS dest wave-uniform base + lane*16
__device__ __forceinline__ void gld16(const void* g, void* l) {
    __builtin_amdgcn_global_load_lds(
        (const __attribute__((address_space(1))) void*)g,
        (__attribute__((address_space(3))) void*)l, 16, 0, 0);
}

// ---------------------------------------------------------------------------
// fp32 -> bf16 cast, vectorized (read 2xfloat4, write short8)
// ---------------------------------------------------------------------------
__global__ __launch_bounds__(256) void f2bf_kernel(
    const float* __restrict__ in, short* __restrict__ out, int n8)
{
    int i = blockIdx.x * 256 + threadIdx.x;
    if (i >= n8) return;
    const float4* p = (const float4*)in;
    float4 x = p[2 * i], y = p[2 * i + 1];
    bf16x8 o;
    o[0] = f2bf(x.x); o[1] = f2bf(x.y); o[2] = f2bf(x.z); o[3] = f2bf(x.w);
    o[4] = f2bf(y.x); o[5] = f2bf(y.y); o[6] = f2bf(y.z); o[7] = f2bf(y.w);
    ((bf16x8*)out)[i] = o;
}

// ---------------------------------------------------------------------------
// RoPE cos/sin tables [T_SEQ][32], fp32 (mimic reference fp32 pipeline)
// ---------------------------------------------------------------------------
__global__ void rope_table_kernel(float* __restrict__ cost, float* __restrict__ sint) {
    int idx = blockIdx.x * 256 + threadIdx.x;
    if (idx >= T_SEQ * 32) return;
    int i = idx & 31, t = idx >> 5;
    float inv = powf(10000.0f, -(float)i / 32.0f);
    float f = (float)t * inv;
    cost[idx] = cosf(f);
    sint[idx] = sinf(f);
}

// ---------------------------------------------------------------------------
// Shared MFMA GEMM core: C(128x128) = A(rowK) * B(rowK)^T, K=EMB, BK=64.
// LDS tiles [128 rows][64 k] bf16 (128B rows), XOR-swizzled (byte^=(row&7)<<4),
// staged via global_load_lds with inverse-swizzled source columns.
// ---------------------------------------------------------------------------
__device__ __forceinline__ void gemm_core(
    const short* __restrict__ A, const short* __restrict__ B,
    char* As, char* Bs, int m0, int n0, int tid, f32x4 (&acc)[4][4])
{
    const int l   = tid & 63;
    const int wid = tid >> 6;
    const int wr  = wid >> 1, wc = wid & 1;

    const int srow = l >> 3;                       // row within 8-row chunk
    const int scol = ((l & 7) ^ srow) << 4;        // inverse-swizzled src col byte
    const int g16  = (l >> 4) << 4;                // k-group byte offset
    const int swx  = (l & 7) << 4;                 // read-side XOR (row&7)<<4

    for (int k0 = 0; k0 < EMB; k0 += 64) {
        __syncthreads();
        #pragma unroll
        for (int c = 0; c < 4; ++c) {
            int ch  = wid * 4 + c;
            int row = ch * 8 + srow;
            gld16((const char*)A + (size_t)(m0 + row) * KBYTES + k0 * 2 + scol,
                  As + ch * 1024);
            gld16((const char*)B + (size_t)(n0 + row) * KBYTES + k0 * 2 + scol,
                  Bs + ch * 1024);
        }
        __syncthreads();
        #pragma unroll
        for (int kk = 0; kk < 2; ++kk) {
            const int cb = (kk * 64 + g16) ^ swx;
            bf16x8 af[4], bfr[4];
            #pragma unroll
            for (int m = 0; m < 4; ++m)
                af[m] = *(const bf16x8*)(As + (wr * 64 + m * 16 + (l & 15)) * 128 + cb);
            #pragma unroll
            for (int n = 0; n < 4; ++n)
                bfr[n] = *(const bf16x8*)(Bs + (wc * 64 + n * 16 + (l & 15)) * 128 + cb);
            #pragma unroll
            for (int m = 0; m < 4; ++m)
                #pragma unroll
                for (int n = 0; n < 4; ++n)
                    acc[m][n] = __builtin_amdgcn_mfma_f32_16x16x32_bf16(
                        af[m], bfr[n], acc[m][n], 0, 0, 0);
        }
    }
}

// ---------------------------------------------------------------------------
// QKV projection (z selects Q/K/V): bf16 out scattered to [B,H,T,D]; Q scaled.
// ---------------------------------------------------------------------------
__global__ __launch_bounds__(256) void qkv_gemm_kernel(
    const short* __restrict__ A,
    const short* __restrict__ B0, const short* __restrict__ B1, const short* __restrict__ B2,
    const float* __restrict__ bias0, const float* __restrict__ bias1, const float* __restrict__ bias2,
    short* __restrict__ O0, short* __restrict__ O1, short* __restrict__ O2)
{
    __shared__ short As_s[8192];
    __shared__ short Bs_s[8192];

    const int z = blockIdx.z;
    const short* B = (z == 0) ? B0 : (z == 1) ? B1 : B2;
    const float* bias = (z == 0) ? bias0 : (z == 1) ? bias1 : bias2;
    short* O = (z == 0) ? O0 : (z == 1) ? O1 : O2;
    const float scale = (z == 0) ? 0.125f : 1.0f;

    const int tid = threadIdx.x;
    const int l = tid & 63;
    const int wid = tid >> 6;
    const int wr = wid >> 1, wc = wid & 1;
    const int m0 = blockIdx.x * 128;
    const int n0 = blockIdx.y * 128;

    f32x4 acc[4][4];
    const f32x4 z4 = {0.f, 0.f, 0.f, 0.f};
    #pragma unroll
    for (int m = 0; m < 4; ++m)
        #pragma unroll
        for (int n = 0; n < 4; ++n) acc[m][n] = z4;

    gemm_core(A, B, (char*)As_s, (char*)Bs_s, m0, n0, tid, acc);

    #pragma unroll
    for (int n = 0; n < 4; ++n) {
        int col = n0 + wc * 64 + n * 16 + (l & 15);
        float bv = bias[col];
        int h = col >> 6, d = col & 63;
        #pragma unroll
        for (int m = 0; m < 4; ++m) {
            #pragma unroll
            for (int r = 0; r < 4; ++r) {
                int row = m0 + wr * 64 + m * 16 + (l >> 4) * 4 + r;
                int t = row >> 3, b = row & 7;
                float v = (acc[m][n][r] + bv) * scale;
                O[((size_t)(b * NH + h) * T_SEQ + t) * HD + d] = f2bf(v);
            }
        }
    }
}

// ---------------------------------------------------------------------------
// Output projection: fp32 out [T,B,E] (row-major [8192][1280]) + bias
// ---------------------------------------------------------------------------
__global__ __launch_bounds__(256) void out_gemm_kernel(
    const short* __restrict__ A, const short* __restrict__ B,
    const float* __restrict__ bias, float* __restrict__ O)
{
    __shared__ short As_s[8192];
    __shared__ short Bs_s[8192];

    const int tid = threadIdx.x;
    const int l = tid & 63;
    const int wid = tid >> 6;
    const int wr = wid >> 1, wc = wid & 1;
    const int m0 = blockIdx.x * 128;
    const int n0 = blockIdx.y * 128;

    f32x4 acc[4][4];
    const f32x4 z4 = {0.f, 0.f, 0.f, 0.f};
    #pragma unroll
    for (int m = 0; m < 4; ++m)
        #pragma unroll
        for (int n = 0; n < 4; ++n) acc[m][n] = z4;

    gemm_core(A, B, (char*)As_s, (char*)Bs_s, m0, n0, tid, acc);

    #pragma unroll
    for (int n = 0; n < 4; ++n) {
        int col = n0 + wc * 64 + n * 16 + (l & 15);
        float bv = bias[col];
        #pragma unroll
        for (int m = 0; m < 4; ++m) {
            #pragma unroll
            for (int r = 0; r < 4; ++r) {
                int row = m0 + wr * 64 + m * 16 + (l >> 4) * 4 + r;
                O[(size_t)row * EMB + col] = acc[m][n][r] + bv;
            }
        }
    }
}

// ---------------------------------------------------------------------------
// RoPE applied in-place to bf16 q,k in [B,H,T,D]; vectorized 8-wide
// ---------------------------------------------------------------------------
__global__ __launch_bounds__(256) void rope_apply_kernel(
    short* __restrict__ q, short* __restrict__ k,
    const float* __restrict__ cost, const float* __restrict__ sint)
{
    int idx = blockIdx.x * 256 + threadIdx.x;   // (bh*1024 + t)*4 + i8
    int i8 = idx & 3;
    int t  = (idx >> 2) & (T_SEQ - 1);
    int bh = idx >> 12;
    size_t base = ((size_t)bh * T_SEQ + t) * HD + i8 * 8;

    float c[8], s[8];
    {
        const float4* cp = (const float4*)(cost + t * 32 + i8 * 8);
        const float4* sp = (const float4*)(sint + t * 32 + i8 * 8);
        float4 c0 = cp[0], c1 = cp[1], s0 = sp[0], s1 = sp[1];
        c[0]=c0.x; c[1]=c0.y; c[2]=c0.z; c[3]=c0.w; c[4]=c1.x; c[5]=c1.y; c[6]=c1.z; c[7]=c1.w;
        s[0]=s0.x; s[1]=s0.y; s[2]=s0.z; s[3]=s0.w; s[4]=s1.x; s[5]=s1.y; s[6]=s1.z; s[7]=s1.w;
    }

    bf16x8 q1 = *(bf16x8*)(q + base), q2 = *(bf16x8*)(q + base + 32);
    bf16x8 k1 = *(bf16x8*)(k + base), k2 = *(bf16x8*)(k + base + 32);
    bf16x8 oq1, oq2, ok1, ok2;
    #pragma unroll
    for (int j = 0; j < 8; ++j) {
        float f1 = bf2f(q1[j]), f2 = bf2f(q2[j]);
        oq1[j] = f2bf(f1 * c[j] - f2 * s[j]);
        oq2[j] = f2bf(f2 * c[j] + f1 * s[j]);
        float g1 = bf2f(k1[j]), g2 = bf2f(k2[j]);
        ok1[j] = f2bf(g1 * c[j] - g2 * s[j]);
        ok2[j] = f2bf(g2 * c[j] + g1 * s[j]);
    }
    *(bf16x8*)(q + base)      = oq1;
    *(bf16x8*)(q + base + 32) = oq2;
    *(bf16x8*)(k + base)      = ok1;
    *(bf16x8*)(k + base + 32) = ok2;
}

// ---------------------------------------------------------------------------
// V transpose per bh: [bh][t][d] -> [bh][d][t], LDS-tiled, coalesced both sides
// ---------------------------------------------------------------------------
__global__ __launch_bounds__(256) void transpose_v_kernel(
    const short* __restrict__ v, short* __restrict__ vt)
{
    __shared__ short tv[64][72];
    const int tid = threadIdx.x;
    const int bh = blockIdx.y, t0 = blockIdx.x * 64;
    const short* src = v + ((size_t)bh * T_SEQ + t0) * HD;
    #pragma unroll
    for (int p = 0; p < 2; ++p) {
        int row = p * 32 + (tid >> 3);
        int c8 = (tid & 7) * 8;
        *(bf16x8*)&tv[row][c8] = *(const bf16x8*)(src + row * HD + c8);
    }
    __syncthreads();
    short* dst = vt + (size_t)bh * (HD * T_SEQ) + t0;
    #pragma unroll
    for (int p = 0; p < 2; ++p) {
        int d = p * 32 + (tid >> 3);
        int t8 = (tid & 7) * 8;
        bf16x8 o;
        #pragma unroll
        for (int j = 0; j < 8; ++j) o[j] = tv[t8 + j][d];
        *(bf16x8*)(dst + (size_t)d * T_SEQ + t8) = o;
    }
}

// ---------------------------------------------------------------------------
// Flash attention, MFMA QK^T + PV. Block = 64 q-rows x one bh, 4 waves
// (wave w owns q-rows w*16..+15). K tiles [kv][d], Vt tiles [d][kv], both
// staged via swizzled global_load_lds. P via wave-local swizzled LDS.
// ---------------------------------------------------------------------------
__global__ __launch_bounds__(256) void attn_kernel(
    const short* __restrict__ Q, const short* __restrict__ K,
    const short* __restrict__ Vt, short* __restrict__ Aout)
{
    __shared__ short Qs_s[4096];
    __shared__ short Ks_s[4096];
    __shared__ short Vs_s[4096];
    __shared__ short Ps_s[4096];
    char* Qs = (char*)Qs_s;
    char* Ks = (char*)Ks_s;
    char* Vs = (char*)Vs_s;
    char* Ps = (char*)Ps_s;

    const int tid = threadIdx.x;
    const int l = tid & 63;
    const int w = tid >> 6;
    const int bh = blockIdx.y;
    const int q0 = blockIdx.x * 64;

    const int srow = l >> 3;
    const int scol = ((l & 7) ^ srow) << 4;
    const int g16  = (l >> 4) << 4;
    const int swx  = (l & 7) << 4;

    const short* Qg = Q + (size_t)bh * (T_SEQ * HD);
    const short* Kg = K + (size_t)bh * (T_SEQ * HD);
    const short* Vg = Vt + (size_t)bh * (HD * T_SEQ);

    // stage Q tile once (8 chunks, 2 per wave)
    #pragma unroll
    for (int c = 0; c < 2; ++c) {
        int ch = w * 2 + c;
        int row = ch * 8 + srow;
        gld16((const char*)Qg + (size_t)(q0 + row) * HD * 2 + scol, Qs + ch * 1024);
    }

    f32x4 oacc[4];
    const f32x4 z4 = {0.f, 0.f, 0.f, 0.f};
    #pragma unroll
    for (int n = 0; n < 4; ++n) oacc[n] = z4;
    float m_i[4], l_i[4];
    #pragma unroll
    for (int r = 0; r < 4; ++r) { m_i[r] = -INFINITY; l_i[r] = 0.f; }

    for (int kt = 0; kt < T_SEQ / 64; ++kt) {
        __syncthreads();
        #pragma unroll
        for (int c = 0; c < 2; ++c) {
            int ch = w * 2 + c;
            int row = ch * 8 + srow;
            gld16((const char*)Kg + (size_t)(kt * 64 + row) * HD * 2 + scol, Ks + ch * 1024);
            gld16((const char*)Vg + ((size_t)row * T_SEQ + kt * 64) * 2 + scol, Vs + ch * 1024);
        }
        __syncthreads();

        // ---- QK^T: M=16 (wave rows), N=64, K=64 ----
        f32x4 sacc[4];
        #pragma unroll
        for (int n = 0; n < 4; ++n) sacc[n] = z4;
        #pragma unroll
        for (int kk = 0; kk < 2; ++kk) {
            const int cb = (kk * 64 + g16) ^ swx;
            bf16x8 aq = *(const bf16x8*)(Qs + (w * 16 + (l & 15)) * 128 + cb);
            #pragma unroll
            for (int n = 0; n < 4; ++n) {
                bf16x8 bk = *(const bf16x8*)(Ks + (n * 16 + (l & 15)) * 128 + cb);
                sacc[n] = __builtin_amdgcn_mfma_f32_16x16x32_bf16(aq, bk, sacc[n], 0, 0, 0);
            }
        }

        // ---- online softmax (row = w*16 + (l>>4)*4 + r, values across l&15) ----
        float corr[4];
        #pragma unroll
        for (int r = 0; r < 4; ++r) {
            float mx = fmaxf(fmaxf(sacc[0][r], sacc[1][r]), fmaxf(sacc[2][r], sacc[3][r]));
            mx = fmaxf(mx, __shfl_xor(mx, 1));
            mx = fmaxf(mx, __shfl_xor(mx, 2));
            mx = fmaxf(mx, __shfl_xor(mx, 4));
            mx = fmaxf(mx, __shfl_xor(mx, 8));
            float mn = fmaxf(m_i[r], mx);
            corr[r] = __expf(m_i[r] - mn);
            m_i[r] = mn;
            int prow = w * 16 + (l >> 4) * 4 + r;
            int pswx = (prow & 7) << 4;
            float rs = 0.f;
            #pragma unroll
            for (int n = 0; n < 4; ++n) {
                float p = __expf(sacc[n][r] - mn);
                rs += p;
                int kv = n * 16 + (l & 15);
                *(short*)(Ps + prow * 128 + ((kv * 2) ^ pswx)) = f2bf(p);
            }
            rs += __shfl_xor(rs, 1);
            rs += __shfl_xor(rs, 2);
            rs += __shfl_xor(rs, 4);
            rs += __shfl_xor(rs, 8);
            l_i[r] = l_i[r] * corr[r] + rs;
        }
        #pragma unroll
        for (int n = 0; n < 4; ++n) {
            f32x4 o = oacc[n];
            o[0] *= corr[0]; o[1] *= corr[1]; o[2] *= corr[2]; o[3] *= corr[3];
            oacc[n] = o;
        }

        // ---- PV: M=16, N=64 (d), K=64 (kv); A=P (wave-local rows), B=Vt ----
        #pragma unroll
        for (int kk = 0; kk < 2; ++kk) {
            const int cb = (kk * 64 + g16) ^ swx;
            bf16x8 ap = *(const bf16x8*)(Ps + (w * 16 + (l & 15)) * 128 + cb);
            #pragma unroll
            for (int n = 0; n < 4; ++n) {
                bf16x8 bv = *(const bf16x8*)(Vs + (n * 16 + (l & 15)) * 128 + cb);
                oacc[n] = __builtin_amdgcn_mfma_f32_16x16x32_bf16(ap, bv, oacc[n], 0, 0, 0);
            }
        }
    }

    // write O as bf16 to [T,B,E] for the out-projection GEMM
    const int b_ = bh / NH, h = bh % NH;
    #pragma unroll
    for (int n = 0; n < 4; ++n) {
        int d = h * HD + n * 16 + (l & 15);
        #pragma unroll
        for (int r = 0; r < 4; ++r) {
            int t = q0 + w * 16 + (l >> 4) * 4 + r;
            float v = oacc[n][r] / l_i[r];
            Aout[((size_t)t * BSZ + b_) * EMB + d] = f2bf(v);
        }
    }
}

// ---------------------------------------------------------------------------
extern "C" void kernel_launch(void* const* d_in, const int* in_sizes, int n_in,
                              void* d_out, int out_size, void* d_ws, size_t ws_size,
                              hipStream_t stream) {
    const float* X     = (const float*)d_in[0];
    const float* q_w   = (const float*)d_in[1];
    const float* q_b   = (const float*)d_in[2];
    const float* k_w   = (const float*)d_in[3];
    const float* k_b   = (const float*)d_in[4];
    const float* v_w   = (const float*)d_in[5];
    const float* v_b   = (const float*)d_in[6];
    const float* out_w = (const float*)d_in[7];
    const float* out_b = (const float*)d_in[8];
    float* out = (float*)d_out;

    short* ws = (short*)d_ws;
    const size_t NACT = (size_t)MROWS * EMB;        // 10485760
    const size_t NW   = (size_t)EMB * EMB;          // 1638400
    short* xb  = ws;
    short* wqb = xb + NACT;
    short* wkb = wqb + NW;
    short* wvb = wkb + NW;
    short* wob = wvb + NW;
    short* qb  = wob + NW;
    short* kb  = qb + NACT;
    short* vb  = kb + NACT;
    short* vtb = vb + NACT;
    short* ab  = vtb + NACT;
    float* cost = (float*)(ab + NACT);
    float* sint = cost + T_SEQ * 32;

    rope_table_kernel<<<dim3(128), 256, 0, stream>>>(cost, sint);
    f2bf_kernel<<<dim3(5120), 256, 0, stream>>>(X, xb, (int)(NACT / 8));
    f2bf_kernel<<<dim3(800), 256, 0, stream>>>(q_w, wqb, (int)(NW / 8));
    f2bf_kernel<<<dim3(800), 256, 0, stream>>>(k_w, wkb, (int)(NW / 8));
    f2bf_kernel<<<dim3(800), 256, 0, stream>>>(v_w, wvb, (int)(NW / 8));
    f2bf_kernel<<<dim3(800), 256, 0, stream>>>(out_w, wob, (int)(NW / 8));

    qkv_gemm_kernel<<<dim3(MROWS / 128, EMB / 128, 3), 256, 0, stream>>>(
        xb, wqb, wkb, wvb, q_b, k_b, v_b, qb, kb, vb);

    rope_apply_kernel<<<dim3(2560), 256, 0, stream>>>(qb, kb, cost, sint);

    transpose_v_kernel<<<dim3(T_SEQ / 64, BSZ * NH), 256, 0, stream>>>(vb, vtb);

    attn_kernel<<<dim3(T_SEQ / 64, BSZ * NH), 256, 0, stream>>>(qb, kb, vtb, ab);

    out_gemm_kernel<<<dim3(MROWS / 128, EMB / 128), 256, 0, stream>>>(
        ab, wob, out_b, out);
}

// Round 3
// 427.815 us; speedup vs baseline: 5.7216x; 1.0408x over previous
//
#include <hip/hip_runtime.h>
#include <math.h>

#define T_SEQ 1024
#define BSZ   8
#define EMB   1280
#define NH    20
#define HD    64
#define MROWS 8192
#define KBYTES (EMB * 2)

typedef __attribute__((ext_vector_type(8))) short bf16x8;
typedef __attribute__((ext_vector_type(4))) float f32x4;

__device__ __forceinline__ short f2bf(float f) {
    unsigned u = __float_as_uint(f);
    u += 0x7fff + ((u >> 16) & 1);           // RNE
    return (short)(u >> 16);
}
__device__ __forceinline__ float bf2f(short s) {
    return __uint_as_float(((unsigned)(unsigned short)s) << 16);
}

// async global->LDS, 16B per lane; LDS dest wave-uniform base + lane*16
__device__ __forceinline__ void gld16(const void* g, void* l) {
    __builtin_amdgcn_global_load_lds(
        (const __attribute__((address_space(1))) void*)g,
        (__attribute__((address_space(3))) void*)l, 16, 0, 0);
}

// ---------------------------------------------------------------------------
// fp32 -> bf16 cast (activations), vectorized
// ---------------------------------------------------------------------------
__global__ __launch_bounds__(256) void f2bf_kernel(
    const float* __restrict__ in, short* __restrict__ out, int n8)
{
    int i = blockIdx.x * 256 + threadIdx.x;
    if (i >= n8) return;
    const float4* p = (const float4*)in;
    float4 x = p[2 * i], y = p[2 * i + 1];
    bf16x8 o;
    o[0] = f2bf(x.x); o[1] = f2bf(x.y); o[2] = f2bf(x.z); o[3] = f2bf(x.w);
    o[4] = f2bf(y.x); o[5] = f2bf(y.y); o[6] = f2bf(y.z); o[7] = f2bf(y.w);
    ((bf16x8*)out)[i] = o;
}

// all four weight matrices in one launch (blockIdx.y selects)
__global__ __launch_bounds__(256) void wcast_kernel(
    const float* __restrict__ w0, const float* __restrict__ w1,
    const float* __restrict__ w2, const float* __restrict__ w3,
    short* __restrict__ o0, short* __restrict__ o1,
    short* __restrict__ o2, short* __restrict__ o3, int n8)
{
    int which = blockIdx.y;
    const float* in = (which == 0) ? w0 : (which == 1) ? w1 : (which == 2) ? w2 : w3;
    short* out      = (which == 0) ? o0 : (which == 1) ? o1 : (which == 2) ? o2 : o3;
    int i = blockIdx.x * 256 + threadIdx.x;
    if (i >= n8) return;
    const float4* p = (const float4*)in;
    float4 x = p[2 * i], y = p[2 * i + 1];
    bf16x8 o;
    o[0] = f2bf(x.x); o[1] = f2bf(x.y); o[2] = f2bf(x.z); o[3] = f2bf(x.w);
    o[4] = f2bf(y.x); o[5] = f2bf(y.y); o[6] = f2bf(y.z); o[7] = f2bf(y.w);
    ((bf16x8*)out)[i] = o;
}

// ---------------------------------------------------------------------------
// RoPE cos/sin tables [T_SEQ][32], fp32
// ---------------------------------------------------------------------------
__global__ void rope_table_kernel(float* __restrict__ cost, float* __restrict__ sint) {
    int idx = blockIdx.x * 256 + threadIdx.x;
    if (idx >= T_SEQ * 32) return;
    int i = idx & 31, t = idx >> 5;
    float inv = powf(10000.0f, -(float)i / 32.0f);
    float f = (float)t * inv;
    cost[idx] = cosf(f);
    sint[idx] = sinf(f);
}

// ---------------------------------------------------------------------------
// Shared MFMA GEMM core: C(128x128) = A(rowK) * B(rowK)^T, K=EMB, BK=64.
// LDS tiles [128 rows][64 k] bf16 (128B rows), XOR-swizzled (byte^=(row&7)<<4),
// staged via global_load_lds with inverse-swizzled source columns.
// (m97-structure; intentionally unchanged this round.)
// ---------------------------------------------------------------------------
__device__ __forceinline__ void gemm_core(
    const short* __restrict__ A, const short* __restrict__ B,
    char* As, char* Bs, int m0, int n0, int tid, f32x4 (&acc)[4][4])
{
    const int l   = tid & 63;
    const int wid = tid >> 6;
    const int wr  = wid >> 1, wc = wid & 1;

    const int srow = l >> 3;                       // row within 8-row chunk
    const int scol = ((l & 7) ^ srow) << 4;        // inverse-swizzled src col byte
    const int g16  = (l >> 4) << 4;                // k-group byte offset
    const int swx  = (l & 7) << 4;                 // read-side XOR (row&7)<<4

    for (int k0 = 0; k0 < EMB; k0 += 64) {
        __syncthreads();
        #pragma unroll
        for (int c = 0; c < 4; ++c) {
            int ch  = wid * 4 + c;
            int row = ch * 8 + srow;
            gld16((const char*)A + (size_t)(m0 + row) * KBYTES + k0 * 2 + scol,
                  As + ch * 1024);
            gld16((const char*)B + (size_t)(n0 + row) * KBYTES + k0 * 2 + scol,
                  Bs + ch * 1024);
        }
        __syncthreads();
        #pragma unroll
        for (int kk = 0; kk < 2; ++kk) {
            const int cb = (kk * 64 + g16) ^ swx;
            bf16x8 af[4], bfr[4];
            #pragma unroll
            for (int m = 0; m < 4; ++m)
                af[m] = *(const bf16x8*)(As + (wr * 64 + m * 16 + (l & 15)) * 128 + cb);
            #pragma unroll
            for (int n = 0; n < 4; ++n)
                bfr[n] = *(const bf16x8*)(Bs + (wc * 64 + n * 16 + (l & 15)) * 128 + cb);
            #pragma unroll
            for (int m = 0; m < 4; ++m)
                #pragma unroll
                for (int n = 0; n < 4; ++n)
                    acc[m][n] = __builtin_amdgcn_mfma_f32_16x16x32_bf16(
                        af[m], bfr[n], acc[m][n], 0, 0, 0);
        }
    }
}

// ---------------------------------------------------------------------------
// QKV projection (z selects Q/K/V): bias + RoPE (z<2) fused in fp32 epilogue,
// bf16 out scattered to [B,H,T,D]; Q pre-scaled by 1/8.
// ---------------------------------------------------------------------------
__global__ __launch_bounds__(256) void qkv_gemm_kernel(
    const short* __restrict__ A,
    const short* __restrict__ B0, const short* __restrict__ B1, const short* __restrict__ B2,
    const float* __restrict__ bias0, const float* __restrict__ bias1, const float* __restrict__ bias2,
    const float* __restrict__ cost, const float* __restrict__ sint,
    short* __restrict__ O0, short* __restrict__ O1, short* __restrict__ O2)
{
    __shared__ short As_s[8192];
    __shared__ short Bs_s[8192];

    const int z = blockIdx.z;
    const short* B = (z == 0) ? B0 : (z == 1) ? B1 : B2;
    const float* bias = (z == 0) ? bias0 : (z == 1) ? bias1 : bias2;
    short* O = (z == 0) ? O0 : (z == 1) ? O1 : O2;
    const float scale = (z == 0) ? 0.125f : 1.0f;

    const int tid = threadIdx.x;
    const int l = tid & 63;
    const int wid = tid >> 6;
    const int wr = wid >> 1, wc = wid & 1;
    const int m0 = blockIdx.x * 128;
    const int n0 = blockIdx.y * 128;

    f32x4 acc[4][4];
    const f32x4 z4 = {0.f, 0.f, 0.f, 0.f};
    #pragma unroll
    for (int m = 0; m < 4; ++m)
        #pragma unroll
        for (int n = 0; n < 4; ++n) acc[m][n] = z4;

    gemm_core(A, B, (char*)As_s, (char*)Bs_s, m0, n0, tid, acc);

    // bias (before rotation, like reference)
    #pragma unroll
    for (int n = 0; n < 4; ++n) {
        int col = n0 + wc * 64 + n * 16 + (l & 15);
        float bv = bias[col];
        #pragma unroll
        for (int m = 0; m < 4; ++m)
            #pragma unroll
            for (int r = 0; r < 4; ++r) acc[m][n][r] += bv;
    }

    // fused RoPE for Q,K: pairs (d, d+32) = (acc[.][n], acc[.][n+2]), n=0,1
    if (z < 2) {
        #pragma unroll
        for (int m = 0; m < 4; ++m) {
            #pragma unroll
            for (int r = 0; r < 4; ++r) {
                int row = m0 + wr * 64 + m * 16 + (l >> 4) * 4 + r;
                int t = row >> 3;
                #pragma unroll
                for (int n = 0; n < 2; ++n) {
                    int i = n * 16 + (l & 15);
                    float c = cost[t * 32 + i];
                    float s = sint[t * 32 + i];
                    float x1 = acc[m][n][r], x2 = acc[m][n + 2][r];
                    acc[m][n][r]     = x1 * c - x2 * s;
                    acc[m][n + 2][r] = x2 * c + x1 * s;
                }
            }
        }
    }

    #pragma unroll
    for (int n = 0; n < 4; ++n) {
        int col = n0 + wc * 64 + n * 16 + (l & 15);
        int h = col >> 6, d = col & 63;
        #pragma unroll
        for (int m = 0; m < 4; ++m) {
            #pragma unroll
            for (int r = 0; r < 4; ++r) {
                int row = m0 + wr * 64 + m * 16 + (l >> 4) * 4 + r;
                int t = row >> 3, b = row & 7;
                O[((size_t)(b * NH + h) * T_SEQ + t) * HD + d] = f2bf(acc[m][n][r] * scale);
            }
        }
    }
}

// ---------------------------------------------------------------------------
// Output projection: fp32 out [T,B,E] + bias
// ---------------------------------------------------------------------------
__global__ __launch_bounds__(256) void out_gemm_kernel(
    const short* __restrict__ A, const short* __restrict__ B,
    const float* __restrict__ bias, float* __restrict__ O)
{
    __shared__ short As_s[8192];
    __shared__ short Bs_s[8192];

    const int tid = threadIdx.x;
    const int l = tid & 63;
    const int wid = tid >> 6;
    const int wr = wid >> 1, wc = wid & 1;
    const int m0 = blockIdx.x * 128;
    const int n0 = blockIdx.y * 128;

    f32x4 acc[4][4];
    const f32x4 z4 = {0.f, 0.f, 0.f, 0.f};
    #pragma unroll
    for (int m = 0; m < 4; ++m)
        #pragma unroll
        for (int n = 0; n < 4; ++n) acc[m][n] = z4;

    gemm_core(A, B, (char*)As_s, (char*)Bs_s, m0, n0, tid, acc);

    #pragma unroll
    for (int n = 0; n < 4; ++n) {
        int col = n0 + wc * 64 + n * 16 + (l & 15);
        float bv = bias[col];
        #pragma unroll
        for (int m = 0; m < 4; ++m) {
            #pragma unroll
            for (int r = 0; r < 4; ++r) {
                int row = m0 + wr * 64 + m * 16 + (l >> 4) * 4 + r;
                O[(size_t)row * EMB + col] = acc[m][n][r] + bv;
            }
        }
    }
}

// ---------------------------------------------------------------------------
// V transpose per bh: [bh][t][d] -> [bh][d][t]
// ---------------------------------------------------------------------------
__global__ __launch_bounds__(256) void transpose_v_kernel(
    const short* __restrict__ v, short* __restrict__ vt)
{
    __shared__ short tv[64][72];
    const int tid = threadIdx.x;
    const int bh = blockIdx.y, t0 = blockIdx.x * 64;
    const short* src = v + ((size_t)bh * T_SEQ + t0) * HD;
    #pragma unroll
    for (int p = 0; p < 2; ++p) {
        int row = p * 32 + (tid >> 3);
        int c8 = (tid & 7) * 8;
        *(bf16x8*)&tv[row][c8] = *(const bf16x8*)(src + row * HD + c8);
    }
    __syncthreads();
    short* dst = vt + (size_t)bh * (HD * T_SEQ) + t0;
    #pragma unroll
    for (int p = 0; p < 2; ++p) {
        int d = p * 32 + (tid >> 3);
        int t8 = (tid & 7) * 8;
        bf16x8 o;
        #pragma unroll
        for (int j = 0; j < 8; ++j) o[j] = tv[t8 + j][d];
        *(bf16x8*)(dst + (size_t)d * T_SEQ + t8) = o;
    }
}

// ---------------------------------------------------------------------------
// Flash attention, MFMA QK^T + PV.  This round:
//  - double-buffered K/V, prefetch issued BEFORE compute, ONE barrier/tile
//  - XCD-aware bijective block swizzle (2560 blocks % 8 == 0)
//  - s_setprio(1) around MFMA clusters
// LDS: Q 8K + K 2x8K + V 2x8K + P 8K = 48 KB -> 3 blocks/CU
// ---------------------------------------------------------------------------
__global__ __launch_bounds__(256) void attn_kernel(
    const short* __restrict__ Q, const short* __restrict__ K,
    const short* __restrict__ Vt, short* __restrict__ Aout)
{
    __shared__ short Qs_s[4096];
    __shared__ short Ks_s[8192];
    __shared__ short Vs_s[8192];
    __shared__ short Ps_s[4096];
    char* Qs = (char*)Qs_s;
    char* Ks = (char*)Ks_s;
    char* Vs = (char*)Vs_s;
    char* Ps = (char*)Ps_s;

    const int tid = threadIdx.x;
    const int l = tid & 63;
    const int w = tid >> 6;

    // XCD swizzle: 16*160 = 2560 blocks, 320 per XCD chunk
    const int bid = blockIdx.y * 16 + blockIdx.x;
    const int swz = (bid & 7) * 320 + (bid >> 3);
    const int q0 = (swz & 15) * 64;
    const int bh = swz >> 4;

    const int srow = l >> 3;
    const int scol = ((l & 7) ^ srow) << 4;
    const int g16  = (l >> 4) << 4;
    const int swx  = (l & 7) << 4;

    const short* Qg = Q + (size_t)bh * (T_SEQ * HD);
    const short* Kg = K + (size_t)bh * (T_SEQ * HD);
    const short* Vg = Vt + (size_t)bh * (HD * T_SEQ);

    // prologue: Q (wave-local rows) + K/V tile 0 into buf 0
    #pragma unroll
    for (int c = 0; c < 2; ++c) {
        int ch = w * 2 + c;
        int row = ch * 8 + srow;
        gld16((const char*)Qg + (size_t)(q0 + row) * HD * 2 + scol, Qs + ch * 1024);
        gld16((const char*)Kg + (size_t)(row) * HD * 2 + scol, Ks + ch * 1024);
        gld16((const char*)Vg + ((size_t)row * T_SEQ) * 2 + scol, Vs + ch * 1024);
    }
    __syncthreads();

    f32x4 oacc[4];
    const f32x4 z4 = {0.f, 0.f, 0.f, 0.f};
    #pragma unroll
    for (int n = 0; n < 4; ++n) oacc[n] = z4;
    float m_i[4], l_i[4];
    #pragma unroll
    for (int r = 0; r < 4; ++r) { m_i[r] = -INFINITY; l_i[r] = 0.f; }

    int buf = 0;
    for (int kt = 0; kt < T_SEQ / 64; ++kt) {
        // issue next tile's loads FIRST (latency hides under compute below)
        if (kt + 1 < T_SEQ / 64) {
            const int ob = (buf ^ 1) * 8192;
            #pragma unroll
            for (int c = 0; c < 2; ++c) {
                int ch = w * 2 + c;
                int row = ch * 8 + srow;
                gld16((const char*)Kg + (size_t)((kt + 1) * 64 + row) * HD * 2 + scol,
                      Ks + ob + ch * 1024);
                gld16((const char*)Vg + ((size_t)row * T_SEQ + (kt + 1) * 64) * 2 + scol,
                      Vs + ob + ch * 1024);
            }
        }
        const int cbuf = buf * 8192;

        // ---- QK^T: M=16 (wave rows), N=64, K=64 ----
        f32x4 sacc[4];
        #pragma unroll
        for (int n = 0; n < 4; ++n) sacc[n] = z4;
        __builtin_amdgcn_s_setprio(1);
        #pragma unroll
        for (int kk = 0; kk < 2; ++kk) {
            const int cb = (kk * 64 + g16) ^ swx;
            bf16x8 aq = *(const bf16x8*)(Qs + (w * 16 + (l & 15)) * 128 + cb);
            #pragma unroll
            for (int n = 0; n < 4; ++n) {
                bf16x8 bk = *(const bf16x8*)(Ks + cbuf + (n * 16 + (l & 15)) * 128 + cb);
                sacc[n] = __builtin_amdgcn_mfma_f32_16x16x32_bf16(aq, bk, sacc[n], 0, 0, 0);
            }
        }
        __builtin_amdgcn_s_setprio(0);

        // ---- online softmax (row = w*16 + (l>>4)*4 + r, values across l&15) ----
        float corr[4];
        #pragma unroll
        for (int r = 0; r < 4; ++r) {
            float mx = fmaxf(fmaxf(sacc[0][r], sacc[1][r]), fmaxf(sacc[2][r], sacc[3][r]));
            mx = fmaxf(mx, __shfl_xor(mx, 1));
            mx = fmaxf(mx, __shfl_xor(mx, 2));
            mx = fmaxf(mx, __shfl_xor(mx, 4));
            mx = fmaxf(mx, __shfl_xor(mx, 8));
            float mn = fmaxf(m_i[r], mx);
            corr[r] = __expf(m_i[r] - mn);
            m_i[r] = mn;
            int prow = w * 16 + (l >> 4) * 4 + r;
            int pswx = (prow & 7) << 4;
            float rs = 0.f;
            #pragma unroll
            for (int n = 0; n < 4; ++n) {
                float p = __expf(sacc[n][r] - mn);
                rs += p;
                int kv = n * 16 + (l & 15);
                *(short*)(Ps + prow * 128 + ((kv * 2) ^ pswx)) = f2bf(p);
            }
            rs += __shfl_xor(rs, 1);
            rs += __shfl_xor(rs, 2);
            rs += __shfl_xor(rs, 4);
            rs += __shfl_xor(rs, 8);
            l_i[r] = l_i[r] * corr[r] + rs;
        }
        #pragma unroll
        for (int n = 0; n < 4; ++n) {
            f32x4 o = oacc[n];
            o[0] *= corr[0]; o[1] *= corr[1]; o[2] *= corr[2]; o[3] *= corr[3];
            oacc[n] = o;
        }

        // ---- PV: M=16, N=64 (d), K=64 (kv); A=P (wave-local), B=Vt ----
        __builtin_amdgcn_s_setprio(1);
        #pragma unroll
        for (int kk = 0; kk < 2; ++kk) {
            const int cb = (kk * 64 + g16) ^ swx;
            bf16x8 ap = *(const bf16x8*)(Ps + (w * 16 + (l & 15)) * 128 + cb);
            #pragma unroll
            for (int n = 0; n < 4; ++n) {
                bf16x8 bv = *(const bf16x8*)(Vs + cbuf + (n * 16 + (l & 15)) * 128 + cb);
                oacc[n] = __builtin_amdgcn_mfma_f32_16x16x32_bf16(ap, bv, oacc[n], 0, 0, 0);
            }
        }
        __builtin_amdgcn_s_setprio(0);

        __syncthreads();   // drains prefetch vmcnt + syncs waves; next tile ready
        buf ^= 1;
    }

    // write O as bf16 to [T,B,E] for the out-projection GEMM
    const int b_ = bh / NH, h = bh % NH;
    #pragma unroll
    for (int n = 0; n < 4; ++n) {
        int d = h * HD + n * 16 + (l & 15);
        #pragma unroll
        for (int r = 0; r < 4; ++r) {
            int t = q0 + w * 16 + (l >> 4) * 4 + r;
            float v = oacc[n][r] / l_i[r];
            Aout[((size_t)t * BSZ + b_) * EMB + d] = f2bf(v);
        }
    }
}

// ---------------------------------------------------------------------------
extern "C" void kernel_launch(void* const* d_in, const int* in_sizes, int n_in,
                              void* d_out, int out_size, void* d_ws, size_t ws_size,
                              hipStream_t stream) {
    const float* X     = (const float*)d_in[0];
    const float* q_w   = (const float*)d_in[1];
    const float* q_b   = (const float*)d_in[2];
    const float* k_w   = (const float*)d_in[3];
    const float* k_b   = (const float*)d_in[4];
    const float* v_w   = (const float*)d_in[5];
    const float* v_b   = (const float*)d_in[6];
    const float* out_w = (const float*)d_in[7];
    const float* out_b = (const float*)d_in[8];
    float* out = (float*)d_out;

    short* ws = (short*)d_ws;
    const size_t NACT = (size_t)MROWS * EMB;        // 10485760
    const size_t NW   = (size_t)EMB * EMB;          // 1638400
    short* xb  = ws;
    short* wqb = xb + NACT;
    short* wkb = wqb + NW;
    short* wvb = wkb + NW;
    short* wob = wvb + NW;
    short* qb  = wob + NW;
    short* kb  = qb + NACT;
    short* vb  = kb + NACT;
    short* vtb = vb + NACT;
    short* ab  = vtb + NACT;
    float* cost = (float*)(ab + NACT);
    float* sint = cost + T_SEQ * 32;

    rope_table_kernel<<<dim3(128), 256, 0, stream>>>(cost, sint);
    f2bf_kernel<<<dim3(5120), 256, 0, stream>>>(X, xb, (int)(NACT / 8));
    wcast_kernel<<<dim3(800, 4), 256, 0, stream>>>(
        q_w, k_w, v_w, out_w, wqb, wkb, wvb, wob, (int)(NW / 8));

    qkv_gemm_kernel<<<dim3(MROWS / 128, EMB / 128, 3), 256, 0, stream>>>(
        xb, wqb, wkb, wvb, q_b, k_b, v_b, cost, sint, qb, kb, vb);

    transpose_v_kernel<<<dim3(T_SEQ / 64, BSZ * NH), 256, 0, stream>>>(vb, vtb);

    attn_kernel<<<dim3(T_SEQ / 64, BSZ * NH), 256, 0, stream>>>(qb, kb, vtb, ab);

    out_gemm_kernel<<<dim3(MROWS / 128, EMB / 128), 256, 0, stream>>>(
        ab, wob, out_b, out);
}

// Round 9
// 377.631 us; speedup vs baseline: 6.4819x; 1.1329x over previous
//
#include <hip/hip_runtime.h>
#include <math.h>

#define T_SEQ 1024
#define BSZ   8
#define EMB   1280
#define NH    20
#define HD    64
#define MROWS 8192
#define KBYTES (EMB * 2)

typedef __attribute__((ext_vector_type(8))) short bf16x8;
typedef __attribute__((ext_vector_type(4))) float f32x4;

__device__ __forceinline__ short f2bf(float f) {
    unsigned u = __float_as_uint(f);
    u += 0x7fff + ((u >> 16) & 1);           // RNE
    return (short)(u >> 16);
}
__device__ __forceinline__ float bf2f(short s) {
    return __uint_as_float(((unsigned)(unsigned short)s) << 16);
}

// async global->LDS, 16B per lane; LDS dest wave-uniform base + lane*16
__device__ __forceinline__ void gld16(const void* g, void* l) {
    __builtin_amdgcn_global_load_lds(
        (const __attribute__((address_space(1))) void*)g,
        (__attribute__((address_space(3))) void*)l, 16, 0, 0);
}

// ---------------------------------------------------------------------------
// fp32 -> bf16 cast (activations), vectorized
// ---------------------------------------------------------------------------
__global__ __launch_bounds__(256) void f2bf_kernel(
    const float* __restrict__ in, short* __restrict__ out, int n8)
{
    int i = blockIdx.x * 256 + threadIdx.x;
    if (i >= n8) return;
    const float4* p = (const float4*)in;
    float4 x = p[2 * i], y = p[2 * i + 1];
    bf16x8 o;
    o[0] = f2bf(x.x); o[1] = f2bf(x.y); o[2] = f2bf(x.z); o[3] = f2bf(x.w);
    o[4] = f2bf(y.x); o[5] = f2bf(y.y); o[6] = f2bf(y.z); o[7] = f2bf(y.w);
    ((bf16x8*)out)[i] = o;
}

// all four weight matrices in one launch (blockIdx.y selects)
__global__ __launch_bounds__(256) void wcast_kernel(
    const float* __restrict__ w0, const float* __restrict__ w1,
    const float* __restrict__ w2, const float* __restrict__ w3,
    short* __restrict__ o0, short* __restrict__ o1,
    short* __restrict__ o2, short* __restrict__ o3, int n8)
{
    int which = blockIdx.y;
    const float* in = (which == 0) ? w0 : (which == 1) ? w1 : (which == 2) ? w2 : w3;
    short* out      = (which == 0) ? o0 : (which == 1) ? o1 : (which == 2) ? o2 : o3;
    int i = blockIdx.x * 256 + threadIdx.x;
    if (i >= n8) return;
    const float4* p = (const float4*)in;
    float4 x = p[2 * i], y = p[2 * i + 1];
    bf16x8 o;
    o[0] = f2bf(x.x); o[1] = f2bf(x.y); o[2] = f2bf(x.z); o[3] = f2bf(x.w);
    o[4] = f2bf(y.x); o[5] = f2bf(y.y); o[6] = f2bf(y.z); o[7] = f2bf(y.w);
    ((bf16x8*)out)[i] = o;
}

// ---------------------------------------------------------------------------
// RoPE cos/sin tables [T_SEQ][32], fp32
// ---------------------------------------------------------------------------
__global__ void rope_table_kernel(float* __restrict__ cost, float* __restrict__ sint) {
    int idx = blockIdx.x * 256 + threadIdx.x;
    if (idx >= T_SEQ * 32) return;
    int i = idx & 31, t = idx >> 5;
    float inv = powf(10000.0f, -(float)i / 32.0f);
    float f = (float)t * inv;
    cost[idx] = cosf(f);
    sint[idx] = sinf(f);
}

// ---------------------------------------------------------------------------
// Shared MFMA GEMM core: C(128x128) = A(rowK) * B(rowK)^T, K=EMB, BK=64.
// LDS tiles [128 rows][64 k] bf16 (128B rows), XOR-swizzled (byte^=(row&7)<<4),
// staged via global_load_lds with inverse-swizzled source columns.
// ---------------------------------------------------------------------------
__device__ __forceinline__ void gemm_core(
    const short* __restrict__ A, const short* __restrict__ B,
    char* As, char* Bs, int m0, int n0, int tid, f32x4 (&acc)[4][4])
{
    const int l   = tid & 63;
    const int wid = tid >> 6;
    const int wr  = wid >> 1, wc = wid & 1;

    const int srow = l >> 3;                       // row within 8-row chunk
    const int scol = ((l & 7) ^ srow) << 4;        // inverse-swizzled src col byte
    const int g16  = (l >> 4) << 4;                // k-group byte offset
    const int swx  = (l & 7) << 4;                 // read-side XOR (row&7)<<4

    for (int k0 = 0; k0 < EMB; k0 += 64) {
        __syncthreads();
        #pragma unroll
        for (int c = 0; c < 4; ++c) {
            int ch  = wid * 4 + c;
            int row = ch * 8 + srow;
            gld16((const char*)A + (size_t)(m0 + row) * KBYTES + k0 * 2 + scol,
                  As + ch * 1024);
            gld16((const char*)B + (size_t)(n0 + row) * KBYTES + k0 * 2 + scol,
                  Bs + ch * 1024);
        }
        __syncthreads();
        #pragma unroll
        for (int kk = 0; kk < 2; ++kk) {
            const int cb = (kk * 64 + g16) ^ swx;
            bf16x8 af[4], bfr[4];
            #pragma unroll
            for (int m = 0; m < 4; ++m)
                af[m] = *(const bf16x8*)(As + (wr * 64 + m * 16 + (l & 15)) * 128 + cb);
            #pragma unroll
            for (int n = 0; n < 4; ++n)
                bfr[n] = *(const bf16x8*)(Bs + (wc * 64 + n * 16 + (l & 15)) * 128 + cb);
            #pragma unroll
            for (int m = 0; m < 4; ++m)
                #pragma unroll
                for (int n = 0; n < 4; ++n)
                    acc[m][n] = __builtin_amdgcn_mfma_f32_16x16x32_bf16(
                        af[m], bfr[n], acc[m][n], 0, 0, 0);
        }
    }
}

// ---------------------------------------------------------------------------
// QKV projection (z selects Q/K/V): bias + RoPE (z<2) fused in fp32 epilogue,
// bf16 out scattered to [B,H,T,D]; Q pre-scaled by 1/8.
// ---------------------------------------------------------------------------
__global__ __launch_bounds__(256) void qkv_gemm_kernel(
    const short* __restrict__ A,
    const short* __restrict__ B0, const short* __restrict__ B1, const short* __restrict__ B2,
    const float* __restrict__ bias0, const float* __restrict__ bias1, const float* __restrict__ bias2,
    const float* __restrict__ cost, const float* __restrict__ sint,
    short* __restrict__ O0, short* __restrict__ O1, short* __restrict__ O2)
{
    __shared__ short As_s[8192];
    __shared__ short Bs_s[8192];

    const int z = blockIdx.z;
    const short* B = (z == 0) ? B0 : (z == 1) ? B1 : B2;
    const float* bias = (z == 0) ? bias0 : (z == 1) ? bias1 : bias2;
    short* O = (z == 0) ? O0 : (z == 1) ? O1 : O2;
    const float scale = (z == 0) ? 0.125f : 1.0f;

    const int tid = threadIdx.x;
    const int l = tid & 63;
    const int wid = tid >> 6;
    const int wr = wid >> 1, wc = wid & 1;
    const int m0 = blockIdx.x * 128;
    const int n0 = blockIdx.y * 128;

    f32x4 acc[4][4];
    const f32x4 z4 = {0.f, 0.f, 0.f, 0.f};
    #pragma unroll
    for (int m = 0; m < 4; ++m)
        #pragma unroll
        for (int n = 0; n < 4; ++n) acc[m][n] = z4;

    gemm_core(A, B, (char*)As_s, (char*)Bs_s, m0, n0, tid, acc);

    // bias (before rotation, like reference)
    #pragma unroll
    for (int n = 0; n < 4; ++n) {
        int col = n0 + wc * 64 + n * 16 + (l & 15);
        float bv = bias[col];
        #pragma unroll
        for (int m = 0; m < 4; ++m)
            #pragma unroll
            for (int r = 0; r < 4; ++r) acc[m][n][r] += bv;
    }

    // fused RoPE for Q,K: pairs (d, d+32) = (acc[.][n], acc[.][n+2]), n=0,1
    if (z < 2) {
        #pragma unroll
        for (int m = 0; m < 4; ++m) {
            #pragma unroll
            for (int r = 0; r < 4; ++r) {
                int row = m0 + wr * 64 + m * 16 + (l >> 4) * 4 + r;
                int t = row >> 3;
                #pragma unroll
                for (int n = 0; n < 2; ++n) {
                    int i = n * 16 + (l & 15);
                    float c = cost[t * 32 + i];
                    float s = sint[t * 32 + i];
                    float x1 = acc[m][n][r], x2 = acc[m][n + 2][r];
                    acc[m][n][r]     = x1 * c - x2 * s;
                    acc[m][n + 2][r] = x2 * c + x1 * s;
                }
            }
        }
    }

    #pragma unroll
    for (int n = 0; n < 4; ++n) {
        int col = n0 + wc * 64 + n * 16 + (l & 15);
        int h = col >> 6, d = col & 63;
        #pragma unroll
        for (int m = 0; m < 4; ++m) {
            #pragma unroll
            for (int r = 0; r < 4; ++r) {
                int row = m0 + wr * 64 + m * 16 + (l >> 4) * 4 + r;
                int t = row >> 3, b = row & 7;
                O[((size_t)(b * NH + h) * T_SEQ + t) * HD + d] = f2bf(acc[m][n][r] * scale);
            }
        }
    }
}

// ---------------------------------------------------------------------------
// Output projection: fp32 out [T,B,E] + bias
// ---------------------------------------------------------------------------
__global__ __launch_bounds__(256) void out_gemm_kernel(
    const short* __restrict__ A, const short* __restrict__ B,
    const float* __restrict__ bias, float* __restrict__ O)
{
    __shared__ short As_s[8192];
    __shared__ short Bs_s[8192];

    const int tid = threadIdx.x;
    const int l = tid & 63;
    const int wid = tid >> 6;
    const int wr = wid >> 1, wc = wid & 1;
    const int m0 = blockIdx.x * 128;
    const int n0 = blockIdx.y * 128;

    f32x4 acc[4][4];
    const f32x4 z4 = {0.f, 0.f, 0.f, 0.f};
    #pragma unroll
    for (int m = 0; m < 4; ++m)
        #pragma unroll
        for (int n = 0; n < 4; ++n) acc[m][n] = z4;

    gemm_core(A, B, (char*)As_s, (char*)Bs_s, m0, n0, tid, acc);

    #pragma unroll
    for (int n = 0; n < 4; ++n) {
        int col = n0 + wc * 64 + n * 16 + (l & 15);
        float bv = bias[col];
        #pragma unroll
        for (int m = 0; m < 4; ++m) {
            #pragma unroll
            for (int r = 0; r < 4; ++r) {
                int row = m0 + wr * 64 + m * 16 + (l >> 4) * 4 + r;
                O[(size_t)row * EMB + col] = acc[m][n][r] + bv;
            }
        }
    }
}

// ---------------------------------------------------------------------------
// V transpose per bh: [bh][t][d] -> [bh][d][t]
// ---------------------------------------------------------------------------
__global__ __launch_bounds__(256) void transpose_v_kernel(
    const short* __restrict__ v, short* __restrict__ vt)
{
    __shared__ short tv[64][72];
    const int tid = threadIdx.x;
    const int bh = blockIdx.y, t0 = blockIdx.x * 64;
    const short* src = v + ((size_t)bh * T_SEQ + t0) * HD;
    #pragma unroll
    for (int p = 0; p < 2; ++p) {
        int row = p * 32 + (tid >> 3);
        int c8 = (tid & 7) * 8;
        *(bf16x8*)&tv[row][c8] = *(const bf16x8*)(src + row * HD + c8);
    }
    __syncthreads();
    short* dst = vt + (size_t)bh * (HD * T_SEQ) + t0;
    #pragma unroll
    for (int p = 0; p < 2; ++p) {
        int d = p * 32 + (tid >> 3);
        int t8 = (tid & 7) * 8;
        bf16x8 o;
        #pragma unroll
        for (int j = 0; j < 8; ++j) o[j] = tv[t8 + j][d];
        *(bf16x8*)(dst + (size_t)d * T_SEQ + t8) = o;
    }
}

// ---------------------------------------------------------------------------
// Flash attention, MFMA QK^T + PV.  SWAPPED QK^T (S^T = K·Q^T) so each lane
// owns one q-row -> softmax is lane-local, P via 4 packed 8B writes,
// defer-max (THR=8), Q fragments in regs.  Q stages through the Ps buffer
// (saves 8KB LDS -> 40KB total -> 4 blocks/CU).  Each wave touches only its
// own 2KB stripe of Ps for both Q-read and P-write, and qf is consumed by
// the first QK^T MFMA before any P-write, so no extra barrier.
// ---------------------------------------------------------------------------
__global__ __launch_bounds__(256) void attn_kernel(
    const short* __restrict__ Q, const short* __restrict__ K,
    const short* __restrict__ Vt, short* __restrict__ Aout)
{
    __shared__ short Ks_s[8192];
    __shared__ short Vs_s[8192];
    __shared__ short Ps_s[4096];    // doubles as the Q staging buffer
    char* Ks = (char*)Ks_s;
    char* Vs = (char*)Vs_s;
    char* Ps = (char*)Ps_s;

    const int tid = threadIdx.x;
    const int l = tid & 63;
    const int w = tid >> 6;
    const int g = l >> 4;               // 16-lane group 0..3

    // XCD swizzle: 16*160 = 2560 blocks, 320 per XCD chunk
    const int bid = blockIdx.y * 16 + blockIdx.x;
    const int swz = (bid & 7) * 320 + (bid >> 3);
    const int q0 = (swz & 15) * 64;
    const int bh = swz >> 4;

    const int srow = l >> 3;
    const int scol = ((l & 7) ^ srow) << 4;
    const int g16  = g << 4;
    const int swx  = (l & 7) << 4;      // read XOR for LDS rows (row&7)==(l&7)

    const short* Qg = Q + (size_t)bh * (T_SEQ * HD);
    const short* Kg = K + (size_t)bh * (T_SEQ * HD);
    const short* Vg = Vt + (size_t)bh * (HD * T_SEQ);

    // prologue: Q tile -> Ps; K/V tile 0 -> buf 0
    #pragma unroll
    for (int c = 0; c < 2; ++c) {
        int ch = w * 2 + c;
        int row = ch * 8 + srow;
        gld16((const char*)Qg + (size_t)(q0 + row) * HD * 2 + scol, Ps + ch * 1024);
        gld16((const char*)Kg + (size_t)(row) * HD * 2 + scol, Ks + ch * 1024);
        gld16((const char*)Vg + ((size_t)row * T_SEQ) * 2 + scol, Vs + ch * 1024);
    }
    __syncthreads();

    // hoist Q fragments (row = w*16 + (l&15)) into registers for all 16 tiles
    bf16x8 qf[2];
    #pragma unroll
    for (int kk = 0; kk < 2; ++kk)
        qf[kk] = *(const bf16x8*)(Ps + (w * 16 + (l & 15)) * 128 + ((kk * 64 + g16) ^ swx));

    f32x4 oacc[4];
    const f32x4 z4 = {0.f, 0.f, 0.f, 0.f};
    #pragma unroll
    for (int n = 0; n < 4; ++n) oacc[n] = z4;
    float m_i = -INFINITY;   // running max of q-row (l&15), replicated over g
    float l_i = 0.f;         // running sum, same row

    const int pbase = (w * 16 + (l & 15)) * 128;   // P row byte base (wave-local)

    int buf = 0;
    for (int kt = 0; kt < T_SEQ / 64; ++kt) {
        // issue next tile's loads FIRST (latency hides under compute below)
        if (kt + 1 < T_SEQ / 64) {
            const int ob = (buf ^ 1) * 8192;
            #pragma unroll
            for (int c = 0; c < 2; ++c) {
                int ch = w * 2 + c;
                int row = ch * 8 + srow;
                gld16((const char*)Kg + (size_t)((kt + 1) * 64 + row) * HD * 2 + scol,
                      Ks + ob + ch * 1024);
                gld16((const char*)Vg + ((size_t)row * T_SEQ + (kt + 1) * 64) * 2 + scol,
                      Vs + ob + ch * 1024);
            }
        }
        const int cbuf = buf * 8192;

        // ---- swapped QK^T: sT[n] rows = kv (n*16 + g*4 + r), col = q (l&15) ----
        f32x4 sT[4];
        #pragma unroll
        for (int n = 0; n < 4; ++n) sT[n] = z4;
        __builtin_amdgcn_s_setprio(1);
        #pragma unroll
        for (int kk = 0; kk < 2; ++kk) {
            const int cb = (kk * 64 + g16) ^ swx;
            #pragma unroll
            for (int n = 0; n < 4; ++n) {
                bf16x8 kf = *(const bf16x8*)(Ks + cbuf + (n * 16 + (l & 15)) * 128 + cb);
                sT[n] = __builtin_amdgcn_mfma_f32_16x16x32_bf16(kf, qf[kk], sT[n], 0, 0, 0);
            }
        }
        __builtin_amdgcn_s_setprio(0);

        // ---- lane-local softmax (lane owns q-row l&15; 16 kv values) ----
        float pmax = fmaxf(fmaxf(sT[0][0], sT[0][1]), fmaxf(sT[0][2], sT[0][3]));
        #pragma unroll
        for (int n = 1; n < 4; ++n)
            pmax = fmaxf(pmax, fmaxf(fmaxf(sT[n][0], sT[n][1]), fmaxf(sT[n][2], sT[n][3])));
        pmax = fmaxf(pmax, __shfl_xor(pmax, 16));
        pmax = fmaxf(pmax, __shfl_xor(pmax, 32));

        if (__any(pmax > m_i + 8.0f)) {            // defer-max: rescale rarely
            float mn = fmaxf(m_i, pmax);
            float corr = __expf(m_i - mn);
            m_i = mn;
            l_i *= corr;
            #pragma unroll
            for (int r = 0; r < 4; ++r) {
                float cp = __shfl(corr, (l & 48) | (g * 4 + r));  // corr of oacc row
                #pragma unroll
                for (int n = 0; n < 4; ++n) oacc[n][r] *= cp;
            }
        }

        float lsum = 0.f;
        #pragma unroll
        for (int n = 0; n < 4; ++n) {
            float p0 = __expf(sT[n][0] - m_i);
            float p1 = __expf(sT[n][1] - m_i);
            float p2 = __expf(sT[n][2] - m_i);
            float p3 = __expf(sT[n][3] - m_i);
            lsum += (p0 + p1) + (p2 + p3);
            unsigned lo = ((unsigned)(unsigned short)f2bf(p0)) |
                          (((unsigned)(unsigned short)f2bf(p1)) << 16);
            unsigned hi = ((unsigned)(unsigned short)f2bf(p2)) |
                          (((unsigned)(unsigned short)f2bf(p3)) << 16);
            uint2 pk; pk.x = lo; pk.y = hi;
            // elements kv = n*16 + g*4 + {0..3} at byte (kv*2) ^ ((row&7)<<4)
            *(uint2*)(Ps + pbase + ((n * 32 + g * 8) ^ swx)) = pk;
        }
        lsum += __shfl_xor(lsum, 16);
        lsum += __shfl_xor(lsum, 32);
        l_i += lsum;

        // ---- PV: M=16 (q-rows), N=64 (d), K=64 (kv); A=P (wave-local), B=Vt ----
        __builtin_amdgcn_s_setprio(1);
        #pragma unroll
        for (int kk = 0; kk < 2; ++kk) {
            const int cb = (kk * 64 + g16) ^ swx;
            bf16x8 ap = *(const bf16x8*)(Ps + pbase + cb);
            #pragma unroll
            for (int n = 0; n < 4; ++n) {
                bf16x8 bv = *(const bf16x8*)(Vs + cbuf + (n * 16 + (l & 15)) * 128 + cb);
                oacc[n] = __builtin_amdgcn_mfma_f32_16x16x32_bf16(ap, bv, oacc[n], 0, 0, 0);
            }
        }
        __builtin_amdgcn_s_setprio(0);

        __syncthreads();   // drains prefetch vmcnt + syncs waves; next tile ready
        buf ^= 1;
    }

    // epilogue: normalize (1/l_i broadcast to oacc rows) and write [T,B,E]
    float inv = 1.0f / l_i;
    float invp[4];
    #pragma unroll
    for (int r = 0; r < 4; ++r) invp[r] = __shfl(inv, (l & 48) | (g * 4 + r));

    const int b_ = bh / NH, h = bh % NH;
    #pragma unroll
    for (int n = 0; n < 4; ++n) {
        int d = h * HD + n * 16 + (l & 15);
        #pragma unroll
        for (int r = 0; r < 4; ++r) {
            int t = q0 + w * 16 + g * 4 + r;
            Aout[((size_t)t * BSZ + b_) * EMB + d] = f2bf(oacc[n][r] * invp[r]);
        }
    }
}

// ---------------------------------------------------------------------------
extern "C" void kernel_launch(void* const* d_in, const int* in_sizes, int n_in,
                              void* d_out, int out_size, void* d_ws, size_t ws_size,
                              hipStream_t stream) {
    const float* X     = (const float*)d_in[0];
    const float* q_w   = (const float*)d_in[1];
    const float* q_b   = (const float*)d_in[2];
    const float* k_w   = (const float*)d_in[3];
    const float* k_b   = (const float*)d_in[4];
    const float* v_w   = (const float*)d_in[5];
    const float* v_b   = (const float*)d_in[6];
    const float* out_w = (const float*)d_in[7];
    const float* out_b = (const float*)d_in[8];
    float* out = (float*)d_out;

    short* ws = (short*)d_ws;
    const size_t NACT = (size_t)MROWS * EMB;        // 10485760
    const size_t NW   = (size_t)EMB * EMB;          // 1638400
    short* xb  = ws;
    short* wqb = xb + NACT;
    short* wkb = wqb + NW;
    short* wvb = wkb + NW;
    short* wob = wvb + NW;
    short* qb  = wob + NW;
    short* kb  = qb + NACT;
    short* vb  = kb + NACT;
    short* vtb = vb + NACT;
    short* ab  = vtb + NACT;
    float* cost = (float*)(ab + NACT);
    float* sint = cost + T_SEQ * 32;

    rope_table_kernel<<<dim3(128), 256, 0, stream>>>(cost, sint);
    f2bf_kernel<<<dim3(5120), 256, 0, stream>>>(X, xb, (int)(NACT / 8));
    wcast_kernel<<<dim3(800, 4), 256, 0, stream>>>(
        q_w, k_w, v_w, out_w, wqb, wkb, wvb, wob, (int)(NW / 8));

    qkv_gemm_kernel<<<dim3(MROWS / 128, EMB / 128, 3), 256, 0, stream>>>(
        xb, wqb, wkb, wvb, q_b, k_b, v_b, cost, sint, qb, kb, vb);

    transpose_v_kernel<<<dim3(T_SEQ / 64, BSZ * NH), 256, 0, stream>>>(vb, vtb);

    attn_kernel<<<dim3(T_SEQ / 64, BSZ * NH), 256, 0, stream>>>(qb, kb, vtb, ab);

    out_gemm_kernel<<<dim3(MROWS / 128, EMB / 128), 256, 0, stream>>>(
        ab, wob, out_b, out);
}